// Round 4
// baseline (125.007 us; speedup 1.0000x reference)
//
#include <hip/hip_runtime.h>
#include <stdint.h>

#define BATCH 4
#define NATOM 1024
#define NTOK  256
#define INF16 0x7FFF

typedef unsigned short u16x8 __attribute__((ext_vector_type(8)));

// ---------------- ws layout (bytes) ----------------
// D0:   [0, 524288)              u16  4*256*256
// D1:   [524288, 1048576)        u16
// tok:  [1048576, 1064960)       int32 4*1024
// g:    [1064960, 1069056)       u8    4*1024
// us:   [1069056, 1070080)       u8    4*256
// L:    [1070080, 1072128)       u16   4*256
#define OFF_D0  0
#define OFF_D1  524288
#define OFF_TOK 1048576
#define OFF_G   1064960
#define OFF_US  1069056
#define OFF_L   1070080

// K0: per-atom argmax(atom_to_token) -> tok, glycan mask -> g, zero 'usable'.
// One wave (64 lanes) per atom; lane reads float4 (coalesced 1KB per wave).
__global__ __launch_bounds__(256) void k_prep(const int* __restrict__ mono,
                                              const float* __restrict__ a2t,
                                              int* __restrict__ tok,
                                              unsigned char* __restrict__ g,
                                              unsigned char* __restrict__ usable) {
    int gtid = blockIdx.x * 256 + threadIdx.x;
    if (gtid < BATCH * NTOK) usable[gtid] = 0;   // zeroed before k_scatter (separate kernel)
    int atom = gtid >> 6;                        // 0..4095
    int lane = threadIdx.x & 63;
    const float* row = a2t + (size_t)atom * NTOK + lane * 4;
    float4 v = *(const float4*)row;
    float mv = v.x; int mi = lane * 4;
    if (v.y > mv) { mv = v.y; mi = lane * 4 + 1; }
    if (v.z > mv) { mv = v.z; mi = lane * 4 + 2; }
    if (v.w > mv) { mv = v.w; mi = lane * 4 + 3; }
    #pragma unroll
    for (int off = 32; off > 0; off >>= 1) {
        float ov = __shfl_down(mv, off);
        int   oi = __shfl_down(mi, off);
        if (ov > mv || (ov == mv && oi < mi)) { mv = ov; mi = oi; }
    }
    if (lane == 0) {
        tok[atom] = mi;
        g[atom]   = (mono[atom] != -1) ? 1 : 0;
    }
}

// K1: scatter usable[b][t] = 1 if any glycan atom maps to token t. Benign write-1 race.
__global__ __launch_bounds__(256) void k_scatter(const int* __restrict__ tok,
                                                 const unsigned char* __restrict__ g,
                                                 unsigned char* __restrict__ usable) {
    int gtid = blockIdx.x * 256 + threadIdx.x;   // 0..4095
    int b = gtid >> 10;
    if (g[gtid]) usable[b * NTOK + tok[gtid]] = 1;
}

// K2: init D0 (u16, INF16=0x7FFF) + same-token loop distance L[t] in {1,2,INF}.
// One block per (b,t) row; thread j handles column j.
__global__ __launch_bounds__(256) void k_init(const float* __restrict__ bonds,
                                              const unsigned char* __restrict__ usable,
                                              unsigned short* __restrict__ D0,
                                              unsigned short* __restrict__ L) {
    int b = blockIdx.x >> 8;
    int t = blockIdx.x & 255;
    int j = threadIdx.x;
    __shared__ int sAny, sSelf;
    if (j == 0) { sAny = 0; sSelf = 0; }
    __syncthreads();
    float f = bonds[(size_t)((b * NTOK + t) * NTOK) + j];
    int bond = (f > 0.0f);
    int uj = usable[b * NTOK + j];
    int ut = usable[b * NTOK + t];
    unsigned short d0 = (j == t) ? 0 : ((bond && ut && uj) ? 1 : INF16);
    D0[(size_t)((b * NTOK + t) * NTOK) + j] = d0;
    if (bond && j != t && uj) sAny = 1;   // benign race (write 1)
    if (bond && j == t) sSelf = 1;
    __syncthreads();
    if (j == 0) L[b * NTOK + t] = sSelf ? 1 : (sAny ? 2 : INF16);
}

// min-plus squaring: C = A (x) A, relies on A symmetric (B-operand read as rows).
// grid: BATCH*64 blocks (32x32 tile each), 256 threads. u16 packed math:
// add never wraps (values <= 0x7FFF -> sums <= 0xFFFE), min via v_pk_min_u16.
__global__ __launch_bounds__(256) void k_square(const unsigned short* __restrict__ Ain,
                                                unsigned short* __restrict__ Aout) {
    int bid = blockIdx.x;
    int b = bid >> 6;
    int tile = bid & 63;
    int ti = ((tile >> 3) & 7) << 5;
    int tj = (tile & 7) << 5;
    const unsigned short* A = Ain + (size_t)b * NTOK * NTOK;
    __shared__ unsigned short Ai[32][264];   // +8 u16 pad: breaks same-bank column reads
    __shared__ unsigned short Aj[32][264];
    int t = threadIdx.x;
    {
        int r = t >> 3, c = t & 7;
        const u16x8* srcI = (const u16x8*)(A + (size_t)(ti + r) * NTOK);
        const u16x8* srcJ = (const u16x8*)(A + (size_t)(tj + r) * NTOK);
        #pragma unroll
        for (int q = 0; q < 4; ++q) {
            int cc = c + q * 8;
            *(u16x8*)&Ai[r][cc * 8] = srcI[cc];
            *(u16x8*)&Aj[r][cc * 8] = srcJ[cc];
        }
    }
    __syncthreads();
    int jj = t & 31, ii0 = t >> 5;           // ii0 in 0..7; rows ii0 + 8p
    u16x8 s0 = {INF16,INF16,INF16,INF16,INF16,INF16,INF16,INF16};
    u16x8 s1 = s0, s2 = s0, s3 = s0;
    for (int k = 0; k < 256; k += 8) {
        u16x8 vb  = *(const u16x8*)&Aj[jj][k];
        u16x8 va0 = *(const u16x8*)&Ai[ii0][k];
        u16x8 va1 = *(const u16x8*)&Ai[ii0 + 8][k];
        u16x8 va2 = *(const u16x8*)&Ai[ii0 + 16][k];
        u16x8 va3 = *(const u16x8*)&Ai[ii0 + 24][k];
        s0 = __builtin_elementwise_min(s0, (u16x8)(va0 + vb));
        s1 = __builtin_elementwise_min(s1, (u16x8)(va1 + vb));
        s2 = __builtin_elementwise_min(s2, (u16x8)(va2 + vb));
        s3 = __builtin_elementwise_min(s3, (u16x8)(va3 + vb));
    }
    unsigned short* out = Aout + (size_t)b * NTOK * NTOK + tj + jj;
    u16x8 ss[4] = {s0, s1, s2, s3};
    #pragma unroll
    for (int p = 0; p < 4; ++p) {
        unsigned m = ss[p][0];
        #pragma unroll
        for (int e = 1; e < 8; ++e) { unsigned x = ss[p][e]; m = (x < m) ? x : m; }
        out[(size_t)(ti + ii0 + 8 * p) * NTOK] = (unsigned short)m;
    }
}

// K11: expand token distances to the (B, N, N) int32 atom output.
// One block per (b, i) row; thread writes int4 (4 columns).
__global__ __launch_bounds__(256) void k_expand(const int* __restrict__ tok,
                                                const unsigned char* __restrict__ g,
                                                const unsigned short* __restrict__ D,
                                                const unsigned short* __restrict__ L,
                                                int* __restrict__ out) {
    int b = blockIdx.x >> 10;
    int i = blockIdx.x & 1023;
    int t4 = threadIdx.x;                 // handles j = 4*t4 .. 4*t4+3
    int base = b * NATOM;
    int ti = tok[base + i];
    int gi = g[base + i];
    const unsigned short* Drow = D + ((size_t)b * NTOK + ti) * NTOK;
    int Li = L[b * NTOK + ti];
    int Lval = (Li <= 255) ? Li : -1;
    int4 tj4 = ((const int4*)(tok + base))[t4];
    uchar4 g4 = ((const uchar4*)(g + base))[t4];
    int j0 = t4 * 4;
    int4 o;
    {
        int j = j0, tj = tj4.x, gj = g4.x;
        o.x = (i == j) ? 0 : ((!gi || !gj) ? -1 : ((tj == ti) ? Lval
              : ((Drow[tj] <= 255) ? (int)Drow[tj] : -1)));
    }
    {
        int j = j0 + 1, tj = tj4.y, gj = g4.y;
        o.y = (i == j) ? 0 : ((!gi || !gj) ? -1 : ((tj == ti) ? Lval
              : ((Drow[tj] <= 255) ? (int)Drow[tj] : -1)));
    }
    {
        int j = j0 + 2, tj = tj4.z, gj = g4.z;
        o.z = (i == j) ? 0 : ((!gi || !gj) ? -1 : ((tj == ti) ? Lval
              : ((Drow[tj] <= 255) ? (int)Drow[tj] : -1)));
    }
    {
        int j = j0 + 3, tj = tj4.w, gj = g4.w;
        o.w = (i == j) ? 0 : ((!gi || !gj) ? -1 : ((tj == ti) ? Lval
              : ((Drow[tj] <= 255) ? (int)Drow[tj] : -1)));
    }
    ((int4*)(out + ((size_t)(base + i)) * NATOM))[t4] = o;
}

extern "C" void kernel_launch(void* const* d_in, const int* in_sizes, int n_in,
                              void* d_out, int out_size, void* d_ws, size_t ws_size,
                              hipStream_t stream) {
    // inputs: [0] atom_pad_mask (unused), [1] atom_mono_idx int32,
    //         [2] token_bonds f32 (B,T,T,1), [3] atom_to_token f32 (B,N,T)
    const int*   mono  = (const int*)d_in[1];
    const float* bonds = (const float*)d_in[2];
    const float* a2t   = (const float*)d_in[3];

    char* ws = (char*)d_ws;
    unsigned short* D0 = (unsigned short*)(ws + OFF_D0);
    unsigned short* D1 = (unsigned short*)(ws + OFF_D1);
    int* tok           = (int*)(ws + OFF_TOK);
    unsigned char* g   = (unsigned char*)(ws + OFF_G);
    unsigned char* us  = (unsigned char*)(ws + OFF_US);
    unsigned short* L  = (unsigned short*)(ws + OFF_L);

    k_prep<<<1024, 256, 0, stream>>>(mono, a2t, tok, g, us);
    k_scatter<<<16, 256, 0, stream>>>(tok, g, us);
    k_init<<<BATCH * NTOK, 256, 0, stream>>>(bonds, us, D0, L);

    unsigned short* pin = D0;
    unsigned short* pout = D1;
    for (int s = 0; s < 8; ++s) {        // 2^8 = 256 >= max path length 255
        k_square<<<BATCH * 64, 256, 0, stream>>>(pin, pout);
        unsigned short* tmp = pin; pin = pout; pout = tmp;
    }
    // result now in pin (== D0 after 8 swaps)
    k_expand<<<BATCH * NATOM, 256, 0, stream>>>(tok, g, pin, L, (int*)d_out);
}

// Round 5
// 82.454 us; speedup vs baseline: 1.5161x; 1.5161x over previous
//
#include <hip/hip_runtime.h>
#include <stdint.h>

#define BATCH 4
#define NATOM 1024
#define NTOK  256

typedef unsigned short u16x8 __attribute__((ext_vector_type(8)));
typedef unsigned long long u64;

// ---------------- ws layout (bytes) ----------------
// adj:  [0, 32768)        u64[1024][4]   raw token adjacency bits (b*256+t rows)
// dist: [32768, 557056)   u16[4][256][256] token APSP (0xFFFF = unreachable)
// tok:  [557056, 573440)  int32[4096]
// g:    [573440, 577536)  u8[4096]
// L:    [577536, 579584)  u16[1024]      same-token loop distance {1,2,0x7FFF}
#define OFF_ADJ  0
#define OFF_DIST 32768
#define OFF_TOK  557056
#define OFF_G    573440
#define OFF_L    577536

// K1: fused prep. Blocks 0..1023: per-atom argmax(atom_to_token) (1 wave/atom)
// + glycan mask. Blocks 1024..1279: token_bonds -> bit adjacency (1 wave/row,
// 4 coalesced float loads + 4 ballots).
__global__ __launch_bounds__(256) void k_prep(const int* __restrict__ mono,
                                              const float* __restrict__ a2t,
                                              const float* __restrict__ bonds,
                                              int* __restrict__ tok,
                                              unsigned char* __restrict__ g,
                                              u64* __restrict__ adjw) {
    int bid  = blockIdx.x;
    int wave = threadIdx.x >> 6;
    int lane = threadIdx.x & 63;
    if (bid < 1024) {
        int atom = bid * 4 + wave;               // 0..4095
        const float* row = a2t + (size_t)atom * NTOK + lane * 4;
        float4 v = *(const float4*)row;
        float mv = v.x; int mi = lane * 4;
        if (v.y > mv) { mv = v.y; mi = lane * 4 + 1; }
        if (v.z > mv) { mv = v.z; mi = lane * 4 + 2; }
        if (v.w > mv) { mv = v.w; mi = lane * 4 + 3; }
        #pragma unroll
        for (int off = 32; off > 0; off >>= 1) {
            float ov = __shfl_down(mv, off);
            int   oi = __shfl_down(mi, off);
            if (ov > mv || (ov == mv && oi < mi)) { mv = ov; mi = oi; }
        }
        if (lane == 0) {
            tok[atom] = mi;
            g[atom]   = (mono[atom] != -1) ? 1 : 0;
        }
    } else {
        int row = (bid - 1024) * 4 + wave;       // 0..1023 == b*256 + t
        const float* p = bonds + (size_t)row * NTOK;
        u64 w0 = __ballot(p[lane]       > 0.0f);
        u64 w1 = __ballot(p[lane + 64]  > 0.0f);
        u64 w2 = __ballot(p[lane + 128] > 0.0f);
        u64 w3 = __ballot(p[lane + 192] > 0.0f);
        if (lane == 0) {
            u64* d = adjw + (size_t)row * 4;
            d[0] = w0; d[1] = w1; d[2] = w2; d[3] = w3;
        }
    }
}

// K2: one block per batch. Build usable mask + masked adjacency + L in LDS,
// then thread s = BFS from source s over 256-bit frontiers (all registers,
// statically indexed). Levels recorded in LDS u16[256][256], flushed coalesced.
// Dynamic LDS: dist 131072 + adjm 8192 + usable 32 = 139296 B (< 160 KB/WG).
__global__ __launch_bounds__(256) void k_bfs(const int* __restrict__ tok,
                                             const unsigned char* __restrict__ g,
                                             const u64* __restrict__ adjw,
                                             unsigned short* __restrict__ distws,
                                             unsigned short* __restrict__ Lws) {
    int b = blockIdx.x;
    int t = threadIdx.x;
    extern __shared__ char smem[];
    unsigned short* dist = (unsigned short*)smem;            // [256*256]
    u64* adjm            = (u64*)(smem + 131072);            // [256*4]
    unsigned* usable32   = (unsigned*)(smem + 131072 + 8192);// [8]

    if (t < 8) usable32[t] = 0;
    // flat conflict-free init of dist to 0xFFFF
    {
        u16x8 ff = {0xFFFF,0xFFFF,0xFFFF,0xFFFF,0xFFFF,0xFFFF,0xFFFF,0xFFFF};
        u16x8* dp = (u16x8*)dist;
        #pragma unroll
        for (int k = 0; k < 32; ++k) dp[t + k * 256] = ff;
    }
    __syncthreads();
    #pragma unroll
    for (int q = 0; q < 4; ++q) {
        int a = b * NATOM + t + q * 256;
        if (g[a]) {
            int tt = tok[a];
            atomicOr(&usable32[tt >> 5], 1u << (tt & 31));
        }
    }
    __syncthreads();
    u64 um0 = ((u64)usable32[1] << 32) | usable32[0];
    u64 um1 = ((u64)usable32[3] << 32) | usable32[2];
    u64 um2 = ((u64)usable32[5] << 32) | usable32[4];
    u64 um3 = ((u64)usable32[7] << 32) | usable32[6];
    // masked adjacency row t + L[t]
    {
        const u64* arow = adjw + (size_t)(b * NTOK + t) * 4;
        u64 a0 = arow[0], a1 = arow[1], a2 = arow[2], a3 = arow[3];
        int w = t >> 6;
        u64 bt = 1ull << (t & 63);
        bool ut = (((w == 0) ? um0 : (w == 1) ? um1 : (w == 2) ? um2 : um3) >> (t & 63)) & 1;
        u64 m0 = ut ? (a0 & um0) : 0ull;
        u64 m1 = ut ? (a1 & um1) : 0ull;
        u64 m2 = ut ? (a2 & um2) : 0ull;
        u64 m3 = ut ? (a3 & um3) : 0ull;
        adjm[t * 4 + 0] = m0; adjm[t * 4 + 1] = m1;
        adjm[t * 4 + 2] = m2; adjm[t * 4 + 3] = m3;
        u64 selfbit = (((w == 0) ? a0 : (w == 1) ? a1 : (w == 2) ? a2 : a3) >> (t & 63)) & 1;
        u64 e0 = m0, e1 = m1, e2 = m2, e3 = m3;
        if (w == 0) e0 &= ~bt; else if (w == 1) e1 &= ~bt;
        else if (w == 2) e2 &= ~bt; else e3 &= ~bt;
        bool nb = (e0 | e1 | e2 | e3) != 0ull;
        Lws[b * NTOK + t] = selfbit ? 1 : (nb ? 2 : 0x7FFF);
    }
    __syncthreads();
    // BFS from source t
    {
        int w = t >> 6;
        u64 bt = 1ull << (t & 63);
        u64 r0 = (w == 0) ? bt : 0ull, r1 = (w == 1) ? bt : 0ull;
        u64 r2 = (w == 2) ? bt : 0ull, r3 = (w == 3) ? bt : 0ull;
        u64 f0 = r0, f1 = r1, f2 = r2, f3 = r3;
        unsigned short* drow = dist + t * 256;
        for (int level = 1; level < 256; ++level) {
            u64 nx0 = 0, nx1 = 0, nx2 = 0, nx3 = 0;
#define EXPAND_WORD(F, W) { u64 f_ = (F); while (f_) { int v_ = ((W) << 6) + __builtin_ctzll(f_); f_ &= f_ - 1; \
            nx0 |= adjm[v_ * 4 + 0]; nx1 |= adjm[v_ * 4 + 1]; nx2 |= adjm[v_ * 4 + 2]; nx3 |= adjm[v_ * 4 + 3]; } }
            EXPAND_WORD(f0, 0) EXPAND_WORD(f1, 1) EXPAND_WORD(f2, 2) EXPAND_WORD(f3, 3)
#undef EXPAND_WORD
            u64 n0 = nx0 & ~r0, n1 = nx1 & ~r1, n2 = nx2 & ~r2, n3 = nx3 & ~r3;
            if (!(n0 | n1 | n2 | n3)) break;
#define RECORD_WORD(NW, W) { u64 n_ = (NW); while (n_) { int v_ = ((W) << 6) + __builtin_ctzll(n_); n_ &= n_ - 1; \
            drow[v_] = (unsigned short)level; } }
            RECORD_WORD(n0, 0) RECORD_WORD(n1, 1) RECORD_WORD(n2, 2) RECORD_WORD(n3, 3)
#undef RECORD_WORD
            r0 |= n0; r1 |= n1; r2 |= n2; r3 |= n3;
            f0 = n0; f1 = n1; f2 = n2; f3 = n3;
        }
    }
    __syncthreads();
    // coalesced flush: 128 KB -> ws
    {
        const u16x8* src = (const u16x8*)dist;
        u16x8* dst = (u16x8*)(distws + (size_t)b * NTOK * NTOK);
        #pragma unroll
        for (int k = 0; k < 32; ++k) dst[t + k * 256] = src[t + k * 256];
    }
}

// K3: expand token distances to the (B, N, N) int32 atom output.
// One block per (b, i) row; thread writes int4 (4 columns).
__global__ __launch_bounds__(256) void k_expand(const int* __restrict__ tok,
                                                const unsigned char* __restrict__ g,
                                                const unsigned short* __restrict__ D,
                                                const unsigned short* __restrict__ L,
                                                int* __restrict__ out) {
    int b = blockIdx.x >> 10;
    int i = blockIdx.x & 1023;
    int t4 = threadIdx.x;                 // handles j = 4*t4 .. 4*t4+3
    int base = b * NATOM;
    int ti = tok[base + i];
    int gi = g[base + i];
    const unsigned short* Drow = D + ((size_t)b * NTOK + ti) * NTOK;
    int Li = L[b * NTOK + ti];
    int Lval = (Li <= 255) ? Li : -1;
    int4 tj4 = ((const int4*)(tok + base))[t4];
    uchar4 g4 = ((const uchar4*)(g + base))[t4];
    int j0 = t4 * 4;
    int4 o;
    {
        int j = j0, tj = tj4.x, gj = g4.x;
        o.x = (i == j) ? 0 : ((!gi || !gj) ? -1 : ((tj == ti) ? Lval
              : ((Drow[tj] <= 255) ? (int)Drow[tj] : -1)));
    }
    {
        int j = j0 + 1, tj = tj4.y, gj = g4.y;
        o.y = (i == j) ? 0 : ((!gi || !gj) ? -1 : ((tj == ti) ? Lval
              : ((Drow[tj] <= 255) ? (int)Drow[tj] : -1)));
    }
    {
        int j = j0 + 2, tj = tj4.z, gj = g4.z;
        o.z = (i == j) ? 0 : ((!gi || !gj) ? -1 : ((tj == ti) ? Lval
              : ((Drow[tj] <= 255) ? (int)Drow[tj] : -1)));
    }
    {
        int j = j0 + 3, tj = tj4.w, gj = g4.w;
        o.w = (i == j) ? 0 : ((!gi || !gj) ? -1 : ((tj == ti) ? Lval
              : ((Drow[tj] <= 255) ? (int)Drow[tj] : -1)));
    }
    ((int4*)(out + ((size_t)(base + i)) * NATOM))[t4] = o;
}

extern "C" void kernel_launch(void* const* d_in, const int* in_sizes, int n_in,
                              void* d_out, int out_size, void* d_ws, size_t ws_size,
                              hipStream_t stream) {
    // inputs: [0] atom_pad_mask (unused), [1] atom_mono_idx int32,
    //         [2] token_bonds f32 (B,T,T,1), [3] atom_to_token f32 (B,N,T)
    const int*   mono  = (const int*)d_in[1];
    const float* bonds = (const float*)d_in[2];
    const float* a2t   = (const float*)d_in[3];

    char* ws = (char*)d_ws;
    u64* adjw           = (u64*)(ws + OFF_ADJ);
    unsigned short* dist = (unsigned short*)(ws + OFF_DIST);
    int* tok            = (int*)(ws + OFF_TOK);
    unsigned char* g    = (unsigned char*)(ws + OFF_G);
    unsigned short* L   = (unsigned short*)(ws + OFF_L);

    k_prep<<<1280, 256, 0, stream>>>(mono, a2t, bonds, tok, g, adjw);
    k_bfs<<<BATCH, 256, 139296, stream>>>(tok, g, adjw, dist, L);
    k_expand<<<BATCH * NATOM, 256, 0, stream>>>(tok, g, dist, L, (int*)d_out);
}

// Round 12
// 81.326 us; speedup vs baseline: 1.5371x; 1.0139x over previous
//
#include <hip/hip_runtime.h>
#include <stdint.h>

#define BATCH 4
#define NATOM 1024
#define NTOK  256

typedef unsigned short u16x8 __attribute__((ext_vector_type(8)));
typedef unsigned long long u64;

// ---------------- ws layout (bytes) ----------------
// adj:  [0, 32768)        u64[1024][4]   raw token adjacency bits (b*256+t rows)
// dist: [32768, 557056)   u16[4][256][256] token APSP (0xFFFF = unreachable)
// tok:  [557056, 573440)  int32[4096]
// g:    [573440, 577536)  u8[4096]
// L:    [577536, 579584)  u16[1024]      same-token loop distance {1,2,0x7FFF}
#define OFF_ADJ  0
#define OFF_DIST 32768
#define OFF_TOK  557056
#define OFF_G    573440
#define OFF_L    577536

// K1: fused prep. Blocks 0..1023: per-atom argmax(atom_to_token) (1 wave/atom)
// + glycan mask. Blocks 1024..1279: token_bonds -> bit adjacency (1 wave/row,
// 4 coalesced float loads + 4 ballots).
__global__ __launch_bounds__(256) void k_prep(const int* __restrict__ mono,
                                              const float* __restrict__ a2t,
                                              const float* __restrict__ bonds,
                                              int* __restrict__ tok,
                                              unsigned char* __restrict__ g,
                                              u64* __restrict__ adjw) {
    int bid  = blockIdx.x;
    int wave = threadIdx.x >> 6;
    int lane = threadIdx.x & 63;
    if (bid < 1024) {
        int atom = bid * 4 + wave;               // 0..4095
        const float* row = a2t + (size_t)atom * NTOK + lane * 4;
        float4 v = *(const float4*)row;
        float mv = v.x; int mi = lane * 4;
        if (v.y > mv) { mv = v.y; mi = lane * 4 + 1; }
        if (v.z > mv) { mv = v.z; mi = lane * 4 + 2; }
        if (v.w > mv) { mv = v.w; mi = lane * 4 + 3; }
        #pragma unroll
        for (int off = 32; off > 0; off >>= 1) {
            float ov = __shfl_down(mv, off);
            int   oi = __shfl_down(mi, off);
            if (ov > mv || (ov == mv && oi < mi)) { mv = ov; mi = oi; }
        }
        if (lane == 0) {
            tok[atom] = mi;
            g[atom]   = (mono[atom] != -1) ? 1 : 0;
        }
    } else {
        int row = (bid - 1024) * 4 + wave;       // 0..1023 == b*256 + t
        const float* p = bonds + (size_t)row * NTOK;
        u64 w0 = __ballot(p[lane]       > 0.0f);
        u64 w1 = __ballot(p[lane + 64]  > 0.0f);
        u64 w2 = __ballot(p[lane + 128] > 0.0f);
        u64 w3 = __ballot(p[lane + 192] > 0.0f);
        if (lane == 0) {
            u64* d = adjw + (size_t)row * 4;
            d[0] = w0; d[1] = w1; d[2] = w2; d[3] = w3;
        }
    }
}

// K2: 16 blocks = (batch, chunk-of-64-sources). 4 lanes per source: lane w owns
// frontier/reached word w (64 bits), expands only its own word's set bits
// (2x ulonglong2 LDS gathers per node), and per level the 4 lanes merge
// partial next-frontiers via __shfl_xor OR-reduce. ~4x shorter serial chain
// than 1-thread-per-source. LDS: dist chunk 32KB + adjm 8KB + usable 32B.
__global__ __launch_bounds__(256) void k_bfs(const int* __restrict__ tok,
                                             const unsigned char* __restrict__ g,
                                             const u64* __restrict__ adjw,
                                             unsigned short* __restrict__ distws,
                                             unsigned short* __restrict__ Lws) {
    int b     = blockIdx.x >> 2;
    int chunk = blockIdx.x & 3;
    int t     = threadIdx.x;
    __shared__ u64 adjm[NTOK * 4];               // 8 KB, masked adjacency
    __shared__ unsigned usable32[8];
    __shared__ unsigned short dist[64 * NTOK];   // 32 KB, this chunk's rows

    if (t < 8) usable32[t] = 0;
    {   // init dist chunk to 0xFFFF (conflict-free u16x8 stores)
        u16x8 ff = {0xFFFF,0xFFFF,0xFFFF,0xFFFF,0xFFFF,0xFFFF,0xFFFF,0xFFFF};
        u16x8* dp = (u16x8*)dist;
        #pragma unroll
        for (int k = 0; k < 8; ++k) dp[t + k * 256] = ff;
    }
    __syncthreads();
    #pragma unroll
    for (int q = 0; q < 4; ++q) {               // usable-token mask for batch b
        int a = b * NATOM + t + q * 256;
        if (g[a]) {
            int tt = tok[a];
            atomicOr(&usable32[tt >> 5], 1u << (tt & 31));
        }
    }
    __syncthreads();
    u64 um0 = ((u64)usable32[1] << 32) | usable32[0];
    u64 um1 = ((u64)usable32[3] << 32) | usable32[2];
    u64 um2 = ((u64)usable32[5] << 32) | usable32[4];
    u64 um3 = ((u64)usable32[7] << 32) | usable32[6];
    {   // masked adjacency row t (+ L[t], written by chunk-0 blocks only)
        const u64* arow = adjw + (size_t)(b * NTOK + t) * 4;
        u64 a0 = arow[0], a1 = arow[1], a2 = arow[2], a3 = arow[3];
        int w = t >> 6;
        u64 bt = 1ull << (t & 63);
        bool ut = (((w == 0) ? um0 : (w == 1) ? um1 : (w == 2) ? um2 : um3) >> (t & 63)) & 1;
        u64 m0 = ut ? (a0 & um0) : 0ull;
        u64 m1 = ut ? (a1 & um1) : 0ull;
        u64 m2 = ut ? (a2 & um2) : 0ull;
        u64 m3 = ut ? (a3 & um3) : 0ull;
        adjm[t * 4 + 0] = m0; adjm[t * 4 + 1] = m1;
        adjm[t * 4 + 2] = m2; adjm[t * 4 + 3] = m3;
        if (chunk == 0) {
            u64 selfbit = (((w == 0) ? a0 : (w == 1) ? a1 : (w == 2) ? a2 : a3) >> (t & 63)) & 1;
            u64 e0 = m0, e1 = m1, e2 = m2, e3 = m3;
            if (w == 0) e0 &= ~bt; else if (w == 1) e1 &= ~bt;
            else if (w == 2) e2 &= ~bt; else e3 &= ~bt;
            bool nb = (e0 | e1 | e2 | e3) != 0ull;
            Lws[b * NTOK + t] = selfbit ? 1 : (nb ? 2 : 0x7FFF);
        }
    }
    __syncthreads();
    {   // BFS: source sl per 4-lane group, lane w owns word w
        int sl = t >> 2;                        // local source 0..63
        int w  = t & 3;                         // owned 64-bit word
        int s  = chunk * 64 + sl;               // global source token
        u64 r = ((s >> 6) == w) ? (1ull << (s & 63)) : 0ull;
        u64 f = r;
        unsigned short* drow = dist + sl * 256;
        const ulonglong2* adj2 = (const ulonglong2*)adjm;
        for (int level = 1; level < 256; ++level) {
            u64 p0 = 0, p1 = 0, p2 = 0, p3 = 0;
            u64 f_ = f;
            while (f_) {
                int v = (w << 6) + __builtin_ctzll(f_);
                f_ &= f_ - 1;
                ulonglong2 q01 = adj2[v * 2];
                ulonglong2 q23 = adj2[v * 2 + 1];
                p0 |= q01.x; p1 |= q01.y; p2 |= q23.x; p3 |= q23.y;
            }
            p0 |= __shfl_xor(p0, 1); p0 |= __shfl_xor(p0, 2);
            p1 |= __shfl_xor(p1, 1); p1 |= __shfl_xor(p1, 2);
            p2 |= __shfl_xor(p2, 1); p2 |= __shfl_xor(p2, 2);
            p3 |= __shfl_xor(p3, 1); p3 |= __shfl_xor(p3, 2);
            u64 full = (w == 0) ? p0 : (w == 1) ? p1 : (w == 2) ? p2 : p3;
            u64 nw = full & ~r;
            int flag = (nw != 0ull);
            flag |= __shfl_xor(flag, 1);
            flag |= __shfl_xor(flag, 2);
            if (!flag) break;
            u64 n_ = nw;
            while (n_) {
                int v = (w << 6) + __builtin_ctzll(n_);
                n_ &= n_ - 1;
                drow[v] = (unsigned short)level;
            }
            r |= nw;
            f = nw;
        }
    }
    __syncthreads();
    {   // coalesced flush of this chunk's 64 rows (32 KB)
        const u16x8* src = (const u16x8*)dist;
        u16x8* dst = (u16x8*)(distws + ((size_t)b * NTOK + chunk * 64) * NTOK);
        #pragma unroll
        for (int k = 0; k < 8; ++k) dst[t + k * 256] = src[t + k * 256];
    }
}

// K3: expand token distances to the (B, N, N) int32 atom output.
// One block per (b, i) row; thread writes int4 (4 columns).
__global__ __launch_bounds__(256) void k_expand(const int* __restrict__ tok,
                                                const unsigned char* __restrict__ g,
                                                const unsigned short* __restrict__ D,
                                                const unsigned short* __restrict__ L,
                                                int* __restrict__ out) {
    int b = blockIdx.x >> 10;
    int i = blockIdx.x & 1023;
    int t4 = threadIdx.x;                 // handles j = 4*t4 .. 4*t4+3
    int base = b * NATOM;
    int ti = tok[base + i];
    int gi = g[base + i];
    const unsigned short* Drow = D + ((size_t)b * NTOK + ti) * NTOK;
    int Li = L[b * NTOK + ti];
    int Lval = (Li <= 255) ? Li : -1;
    int4 tj4 = ((const int4*)(tok + base))[t4];
    uchar4 g4 = ((const uchar4*)(g + base))[t4];
    int j0 = t4 * 4;
    int4 o;
    {
        int j = j0, tj = tj4.x, gj = g4.x;
        o.x = (i == j) ? 0 : ((!gi || !gj) ? -1 : ((tj == ti) ? Lval
              : ((Drow[tj] <= 255) ? (int)Drow[tj] : -1)));
    }
    {
        int j = j0 + 1, tj = tj4.y, gj = g4.y;
        o.y = (i == j) ? 0 : ((!gi || !gj) ? -1 : ((tj == ti) ? Lval
              : ((Drow[tj] <= 255) ? (int)Drow[tj] : -1)));
    }
    {
        int j = j0 + 2, tj = tj4.z, gj = g4.z;
        o.z = (i == j) ? 0 : ((!gi || !gj) ? -1 : ((tj == ti) ? Lval
              : ((Drow[tj] <= 255) ? (int)Drow[tj] : -1)));
    }
    {
        int j = j0 + 3, tj = tj4.w, gj = g4.w;
        o.w = (i == j) ? 0 : ((!gi || !gj) ? -1 : ((tj == ti) ? Lval
              : ((Drow[tj] <= 255) ? (int)Drow[tj] : -1)));
    }
    ((int4*)(out + ((size_t)(base + i)) * NATOM))[t4] = o;
}

extern "C" void kernel_launch(void* const* d_in, const int* in_sizes, int n_in,
                              void* d_out, int out_size, void* d_ws, size_t ws_size,
                              hipStream_t stream) {
    // inputs: [0] atom_pad_mask (unused), [1] atom_mono_idx int32,
    //         [2] token_bonds f32 (B,T,T,1), [3] atom_to_token f32 (B,N,T)
    const int*   mono  = (const int*)d_in[1];
    const float* bonds = (const float*)d_in[2];
    const float* a2t   = (const float*)d_in[3];

    char* ws = (char*)d_ws;
    u64* adjw            = (u64*)(ws + OFF_ADJ);
    unsigned short* dist = (unsigned short*)(ws + OFF_DIST);
    int* tok             = (int*)(ws + OFF_TOK);
    unsigned char* g     = (unsigned char*)(ws + OFF_G);
    unsigned short* L    = (unsigned short*)(ws + OFF_L);

    k_prep<<<1280, 256, 0, stream>>>(mono, a2t, bonds, tok, g, adjw);
    k_bfs<<<16, 256, 0, stream>>>(tok, g, adjw, dist, L);
    k_expand<<<BATCH * NATOM, 256, 0, stream>>>(tok, g, dist, L, (int*)d_out);
}